// Round 3
// baseline (1019.498 us; speedup 1.0000x reference)
//
#include <hip/hip_runtime.h>
#include <math.h>

#define NQ 4
#define NL 2

// Fused kernel: per-block quantum-circuit collapse (A = Re(M^+ D M), 16x16,
// in LDS) + 2 samples per thread so every float4 weight load feeds 8 FMAs.
// __launch_bounds__(256,2): 256-VGPR budget -> h-accumulators stay in VGPRs
// (round 2's 64-VGPR allocation shuffled them through AGPRs).
__global__ __launch_bounds__(256, 2) void qnn_fused(
    const float* __restrict__ text, const float* __restrict__ image,
    const float* __restrict__ tW1, const float* __restrict__ tb1,
    const float* __restrict__ tW2, const float* __restrict__ tb2,
    const float* __restrict__ iW1, const float* __restrict__ ib1,
    const float* __restrict__ iW2, const float* __restrict__ ib2,
    const float* __restrict__ qw,
    const float* __restrict__ cW1, const float* __restrict__ cb1,
    const float* __restrict__ cW2, const float* __restrict__ cb2,
    float* __restrict__ out, int B)
{
    __shared__ float Mre[16][16], Mim[16][16], As[16][16];
    const int tid = threadIdx.x;

    // ---- phase 1: build A (depends only on qweights; ~1 us, paid per block)
    if (tid < 16) {
        const int j = tid;
        float re[16], im[16];
        #pragma unroll
        for (int b = 0; b < 16; ++b) { re[b] = (b == j) ? 1.f : 0.f; im[b] = 0.f; }
        for (int l = 0; l < NL; ++l) {
            for (int i = 0; i < NQ; ++i) {
                float phi   = qw[(l*NQ + i)*3 + 0];
                float theta = qw[(l*NQ + i)*3 + 1];
                float omega = qw[(l*NQ + i)*3 + 2];
                float ct, st; __sincosf(0.5f*theta, &st, &ct);
                float cap, sap, cam, sam;
                __sincosf(0.5f*(phi + omega), &sap, &cap);
                __sincosf(0.5f*(phi - omega), &sam, &cam);
                // Rot = RZ(omega)RY(theta)RZ(phi)
                float u00r =  cap*ct, u00i = -sap*ct;
                float u01r = -cam*st, u01i = -sam*st;
                float u10r =  cam*st, u10i = -sam*st;
                float u11r =  cap*ct, u11i =  sap*ct;
                int mask = 1 << (3 - i);   // wire i lives on bit (3-i)
                #pragma unroll
                for (int b = 0; b < 16; ++b) {
                    if (b & mask) continue;
                    int b1 = b | mask;
                    float a0r = re[b],  a0i = im[b];
                    float a1r = re[b1], a1i = im[b1];
                    re[b]  = u00r*a0r - u00i*a0i + u01r*a1r - u01i*a1i;
                    im[b]  = u00r*a0i + u00i*a0r + u01r*a1i + u01i*a1r;
                    re[b1] = u10r*a0r - u10i*a0i + u11r*a1r - u11i*a1i;
                    im[b1] = u10r*a0i + u10i*a0r + u11r*a1i + u11i*a1r;
                }
            }
            #pragma unroll
            for (int b = 0; b < 16; ++b) {   // CZ chain masks 0xC,0x6,0x3
                float sgn = 1.f;
                if ((b & 0xC) == 0xC) sgn = -sgn;
                if ((b & 0x6) == 0x6) sgn = -sgn;
                if ((b & 0x3) == 0x3) sgn = -sgn;
                re[b] *= sgn; im[b] *= sgn;
            }
        }
        #pragma unroll
        for (int b = 0; b < 16; ++b) { Mre[j][b] = re[b]; Mim[j][b] = im[b]; }
    }
    __syncthreads();
    {
        int j = tid >> 4, k = tid & 15;
        float sacc = 0.f;
        #pragma unroll
        for (int b = 0; b < 16; ++b) {
            float sg = (b & 8) ? -1.f : 1.f;   // bit 3 == wire 0
            sacc += sg * (Mre[j][b]*Mre[k][b] + Mim[j][b]*Mim[k][b]);
        }
        As[j][k] = sacc;
    }
    __syncthreads();

    // ---- phase 2: two samples per thread
    const int s0 = blockIdx.x * 512 + tid;
    const int s1 = s0 + 256;
    const int c0 = (s0 < B) ? s0 : (B - 1);
    const int c1 = (s1 < B) ? s1 : (B - 1);

    // ---- image MLP: [48] -> relu[64] -> [4], full 64 accumulators x2 samples
    float a0[64], a1[64];
    {
        const float4* bb = (const float4*)ib1;
        #pragma unroll
        for (int j4 = 0; j4 < 16; ++j4) {
            float4 bv = bb[j4];
            a0[4*j4] = bv.x; a0[4*j4+1] = bv.y; a0[4*j4+2] = bv.z; a0[4*j4+3] = bv.w;
            a1[4*j4] = bv.x; a1[4*j4+1] = bv.y; a1[4*j4+2] = bv.z; a1[4*j4+3] = bv.w;
        }
    }
    {
        const float4* i40 = (const float4*)(image + (size_t)c0 * 48);
        const float4* i41 = (const float4*)(image + (size_t)c1 * 48);
        #pragma unroll 2
        for (int k4 = 0; k4 < 12; ++k4) {
            float4 v0 = i40[k4];
            float4 v1 = i41[k4];
            const float4* wr = (const float4*)(iW1 + k4 * 4 * 64);
            #pragma unroll
            for (int kk = 0; kk < 4; ++kk) {
                float e0 = (kk == 0) ? v0.x : (kk == 1) ? v0.y : (kk == 2) ? v0.z : v0.w;
                float e1 = (kk == 0) ? v1.x : (kk == 1) ? v1.y : (kk == 2) ? v1.z : v1.w;
                #pragma unroll
                for (int j4 = 0; j4 < 16; ++j4) {
                    float4 w = wr[kk*16 + j4];
                    a0[4*j4]   = fmaf(e0, w.x, a0[4*j4]);
                    a0[4*j4+1] = fmaf(e0, w.y, a0[4*j4+1]);
                    a0[4*j4+2] = fmaf(e0, w.z, a0[4*j4+2]);
                    a0[4*j4+3] = fmaf(e0, w.w, a0[4*j4+3]);
                    a1[4*j4]   = fmaf(e1, w.x, a1[4*j4]);
                    a1[4*j4+1] = fmaf(e1, w.y, a1[4*j4+1]);
                    a1[4*j4+2] = fmaf(e1, w.z, a1[4*j4+2]);
                    a1[4*j4+3] = fmaf(e1, w.w, a1[4*j4+3]);
                }
            }
        }
    }
    float imf0[4], imf1[4];
    {
        float4 b2 = *(const float4*)ib2;
        imf0[0] = b2.x; imf0[1] = b2.y; imf0[2] = b2.z; imf0[3] = b2.w;
        imf1[0] = b2.x; imf1[1] = b2.y; imf1[2] = b2.z; imf1[3] = b2.w;
        #pragma unroll 8
        for (int j = 0; j < 64; ++j) {
            float4 w2 = *(const float4*)(iW2 + j * 4);
            float r0 = fmaxf(a0[j], 0.f);
            float r1 = fmaxf(a1[j], 0.f);
            imf0[0] = fmaf(r0, w2.x, imf0[0]); imf0[1] = fmaf(r0, w2.y, imf0[1]);
            imf0[2] = fmaf(r0, w2.z, imf0[2]); imf0[3] = fmaf(r0, w2.w, imf0[3]);
            imf1[0] = fmaf(r1, w2.x, imf1[0]); imf1[1] = fmaf(r1, w2.y, imf1[1]);
            imf1[2] = fmaf(r1, w2.z, imf1[2]); imf1[3] = fmaf(r1, w2.w, imf1[3]);
        }
    }

    // ---- text MLP: [16] -> relu[32] -> [4]  (reuses low half of a0/a1)
    {
        const float4* bb = (const float4*)tb1;
        #pragma unroll
        for (int j4 = 0; j4 < 8; ++j4) {
            float4 bv = bb[j4];
            a0[4*j4] = bv.x; a0[4*j4+1] = bv.y; a0[4*j4+2] = bv.z; a0[4*j4+3] = bv.w;
            a1[4*j4] = bv.x; a1[4*j4+1] = bv.y; a1[4*j4+2] = bv.z; a1[4*j4+3] = bv.w;
        }
        const float4* t40 = (const float4*)(text + (size_t)c0 * 16);
        const float4* t41 = (const float4*)(text + (size_t)c1 * 16);
        #pragma unroll
        for (int k4 = 0; k4 < 4; ++k4) {
            float4 v0 = t40[k4];
            float4 v1 = t41[k4];
            const float4* wr = (const float4*)(tW1 + k4 * 4 * 32);
            #pragma unroll
            for (int kk = 0; kk < 4; ++kk) {
                float e0 = (kk == 0) ? v0.x : (kk == 1) ? v0.y : (kk == 2) ? v0.z : v0.w;
                float e1 = (kk == 0) ? v1.x : (kk == 1) ? v1.y : (kk == 2) ? v1.z : v1.w;
                #pragma unroll
                for (int j4 = 0; j4 < 8; ++j4) {
                    float4 w = wr[kk*8 + j4];
                    a0[4*j4]   = fmaf(e0, w.x, a0[4*j4]);
                    a0[4*j4+1] = fmaf(e0, w.y, a0[4*j4+1]);
                    a0[4*j4+2] = fmaf(e0, w.z, a0[4*j4+2]);
                    a0[4*j4+3] = fmaf(e0, w.w, a0[4*j4+3]);
                    a1[4*j4]   = fmaf(e1, w.x, a1[4*j4]);
                    a1[4*j4+1] = fmaf(e1, w.y, a1[4*j4+1]);
                    a1[4*j4+2] = fmaf(e1, w.z, a1[4*j4+2]);
                    a1[4*j4+3] = fmaf(e1, w.w, a1[4*j4+3]);
                }
            }
        }
    }
    float tf0[4], tf1[4];
    {
        float4 b2 = *(const float4*)tb2;
        tf0[0] = b2.x; tf0[1] = b2.y; tf0[2] = b2.z; tf0[3] = b2.w;
        tf1[0] = b2.x; tf1[1] = b2.y; tf1[2] = b2.z; tf1[3] = b2.w;
        #pragma unroll 8
        for (int j = 0; j < 32; ++j) {
            float4 w2 = *(const float4*)(tW2 + j * 4);
            float r0 = fmaxf(a0[j], 0.f);
            float r1 = fmaxf(a1[j], 0.f);
            tf0[0] = fmaf(r0, w2.x, tf0[0]); tf0[1] = fmaf(r0, w2.y, tf0[1]);
            tf0[2] = fmaf(r0, w2.z, tf0[2]); tf0[3] = fmaf(r0, w2.w, tf0[3]);
            tf1[0] = fmaf(r1, w2.x, tf1[0]); tf1[1] = fmaf(r1, w2.y, tf1[1]);
            tf1[2] = fmaf(r1, w2.z, tf1[2]); tf1[3] = fmaf(r1, w2.w, tf1[3]);
        }
    }

    // ---- quantum expectation: q = psi^T A psi, angle = (tf+imf)*0.25
    float psi0[16], psi1[16];
    {
        float c[4], s[4];
        #pragma unroll
        for (int i = 0; i < 4; ++i) {
            float f = (tf0[i] + imf0[i]) * 0.25f;
            __sincosf(f, &s[i], &c[i]);
        }
        float p01[4] = { c[0]*c[1], c[0]*s[1], s[0]*c[1], s[0]*s[1] };
        float p23[4] = { c[2]*c[3], c[2]*s[3], s[2]*c[3], s[2]*s[3] };
        #pragma unroll
        for (int x = 0; x < 4; ++x)
            #pragma unroll
            for (int y = 0; y < 4; ++y)
                psi0[x*4+y] = p01[x] * p23[y];
        #pragma unroll
        for (int i = 0; i < 4; ++i) {
            float f = (tf1[i] + imf1[i]) * 0.25f;
            __sincosf(f, &s[i], &c[i]);
        }
        float q01[4] = { c[0]*c[1], c[0]*s[1], s[0]*c[1], s[0]*s[1] };
        float q23[4] = { c[2]*c[3], c[2]*s[3], s[2]*c[3], s[2]*s[3] };
        #pragma unroll
        for (int x = 0; x < 4; ++x)
            #pragma unroll
            for (int y = 0; y < 4; ++y)
                psi1[x*4+y] = q01[x] * q23[y];
    }
    float q0 = 0.f, q1 = 0.f;
    #pragma unroll
    for (int j = 0; j < 16; ++j) {
        float r0 = 0.f, r1 = 0.f;
        #pragma unroll
        for (int k4 = 0; k4 < 4; ++k4) {
            float4 av = *(const float4*)&As[j][k4*4];   // LDS broadcast
            r0 = fmaf(av.x, psi0[k4*4+0], r0); r0 = fmaf(av.y, psi0[k4*4+1], r0);
            r0 = fmaf(av.z, psi0[k4*4+2], r0); r0 = fmaf(av.w, psi0[k4*4+3], r0);
            r1 = fmaf(av.x, psi1[k4*4+0], r1); r1 = fmaf(av.y, psi1[k4*4+1], r1);
            r1 = fmaf(av.z, psi1[k4*4+2], r1); r1 = fmaf(av.w, psi1[k4*4+3], r1);
        }
        q0 = fmaf(psi0[j], r0, q0);
        q1 = fmaf(psi1[j], r1, q1);
    }

    // ---- classifier head
    float2 ob = *(const float2*)cb2;
    float o00 = ob.x, o01 = ob.y, o10 = ob.x, o11 = ob.y;
    #pragma unroll
    for (int j = 0; j < 16; ++j) {
        float w1 = cW1[j], b1v = cb1[j];
        float2 w2 = *(const float2*)(cW2 + j*2);
        float h0 = fmaxf(fmaf(q0, w1, b1v), 0.f);
        float h1 = fmaxf(fmaf(q1, w1, b1v), 0.f);
        o00 = fmaf(h0, w2.x, o00); o01 = fmaf(h0, w2.y, o01);
        o10 = fmaf(h1, w2.x, o10); o11 = fmaf(h1, w2.y, o11);
    }
    float2* o2 = (float2*)out;
    if (s0 < B) o2[s0] = make_float2(o00, o01);
    if (s1 < B) o2[s1] = make_float2(o10, o11);
}

extern "C" void kernel_launch(void* const* d_in, const int* in_sizes, int n_in,
                              void* d_out, int out_size, void* d_ws, size_t ws_size,
                              hipStream_t stream)
{
    const float* text  = (const float*)d_in[0];
    const float* image = (const float*)d_in[1];
    const float* tW1   = (const float*)d_in[2];
    const float* tb1   = (const float*)d_in[3];
    const float* tW2   = (const float*)d_in[4];
    const float* tb2   = (const float*)d_in[5];
    const float* iW1   = (const float*)d_in[6];
    const float* ib1   = (const float*)d_in[7];
    const float* iW2   = (const float*)d_in[8];
    const float* ib2   = (const float*)d_in[9];
    const float* qw    = (const float*)d_in[10];
    const float* cW1   = (const float*)d_in[11];
    const float* cb1   = (const float*)d_in[12];
    const float* cW2   = (const float*)d_in[13];
    const float* cb2   = (const float*)d_in[14];

    int B = in_sizes[0] / 16;
    int grid = (B + 511) / 512;   // 2 samples per thread, 256 threads/block

    qnn_fused<<<grid, 256, 0, stream>>>(
        text, image, tW1, tb1, tW2, tb2, iW1, ib1, iW2, ib2,
        qw, cW1, cb1, cW2, cb2, (float*)d_out, B);
}

// Round 4
// 416.262 us; speedup vs baseline: 2.4492x; 2.4492x over previous
//
#include <hip/hip_runtime.h>
#include <math.h>

#define NQ 4
#define NL 2

typedef float v2f __attribute__((ext_vector_type(2)));

static __device__ __forceinline__ v2f vsplat(float x) { v2f r; r.x = x; r.y = x; return r; }
static __device__ __forceinline__ v2f vfma(v2f a, float b, v2f c) {
#if __has_builtin(__builtin_elementwise_fma)
    return __builtin_elementwise_fma(a, vsplat(b), c);
#else
    v2f r; r.x = __builtin_fmaf(a.x, b, c.x); r.y = __builtin_fmaf(a.y, b, c.y); return r;
#endif
}
static __device__ __forceinline__ v2f vfmav(v2f a, v2f b, v2f c) {
#if __has_builtin(__builtin_elementwise_fma)
    return __builtin_elementwise_fma(a, b, c);
#else
    v2f r; r.x = __builtin_fmaf(a.x, b.x, c.x); r.y = __builtin_fmaf(a.y, b.y, c.y); return r;
#endif
}
static __device__ __forceinline__ v2f vrelu(v2f a) {
    v2f r; r.x = fmaxf(a.x, 0.f); r.y = fmaxf(a.y, 0.f); return r;
}
static __device__ __forceinline__ float fget(float4 v, int k) {
    return (k == 0) ? v.x : (k == 1) ? v.y : (k == 2) ? v.z : v.w;
}

// LDS layout (float indices; all region starts multiple of 4 -> 16B aligned)
#define O_IW1 0       // 48x64
#define O_IW2 3072    // 64x4
#define O_TW1 3328    // 16x32
#define O_TW2 3840    // 32x4
#define O_IB1 3968    // 64
#define O_TB1 4032    // 32
#define O_FB2 4064    // 4   (ib2+tb2)
#define O_CW1 4068    // 16
#define O_CB1 4084    // 16
#define O_CW2 4100    // 32
#define O_CB2 4132    // 2
#define O_AS  4136    // 16x16
#define O_MRE 4392    // 16x16 scratch
#define O_MIM 4648    // 16x16 scratch
#define LDS_FLOATS 4904

// 4 samples/thread (2 packed float2 pairs), weights broadcast from LDS,
// image neurons strip-mined in quarters of 16 -> acc = 64 VGPRs, no spills.
// Register demand ~120 -> __launch_bounds__(256,3) gives ~170 budget headroom.
__global__ __launch_bounds__(256, 3) void qnn_fused(
    const float* __restrict__ text, const float* __restrict__ image,
    const float* __restrict__ tW1, const float* __restrict__ tb1,
    const float* __restrict__ tW2, const float* __restrict__ tb2,
    const float* __restrict__ iW1, const float* __restrict__ ib1,
    const float* __restrict__ iW2, const float* __restrict__ ib2,
    const float* __restrict__ qw,
    const float* __restrict__ cW1, const float* __restrict__ cb1,
    const float* __restrict__ cW2, const float* __restrict__ cb2,
    float* __restrict__ out, int B)
{
    __shared__ __align__(16) float W[LDS_FLOATS];
    const int tid = threadIdx.x;

    // ---- stage weights into LDS (coalesced, once per block / 1024 samples)
    for (int i = tid; i < 3072; i += 256) W[O_IW1 + i] = iW1[i];
    W[O_IW2 + tid] = iW2[tid];                      // exactly 256
    for (int i = tid; i < 512; i += 256) W[O_TW1 + i] = tW1[i];
    if (tid < 128) W[O_TW2 + tid] = tW2[tid];
    if (tid < 64)  W[O_IB1 + tid] = ib1[tid];
    if (tid < 32)  W[O_TB1 + tid] = tb1[tid];
    if (tid < 4)   W[O_FB2 + tid] = ib2[tid] + tb2[tid];
    if (tid < 16) { W[O_CW1 + tid] = cW1[tid]; W[O_CB1 + tid] = cb1[tid]; }
    if (tid < 32)  W[O_CW2 + tid] = cW2[tid];
    if (tid < 2)   W[O_CB2 + tid] = cb2[tid];

    // ---- simulate circuit columns (16 threads), then reduce to A (256 thr)
    if (tid < 16) {
        const int j = tid;
        float re[16], im[16];
        #pragma unroll
        for (int b = 0; b < 16; ++b) { re[b] = (b == j) ? 1.f : 0.f; im[b] = 0.f; }
        for (int l = 0; l < NL; ++l) {
            for (int i = 0; i < NQ; ++i) {
                float phi   = qw[(l*NQ + i)*3 + 0];
                float theta = qw[(l*NQ + i)*3 + 1];
                float omega = qw[(l*NQ + i)*3 + 2];
                float ct, st; __sincosf(0.5f*theta, &st, &ct);
                float cap, sap, cam, sam;
                __sincosf(0.5f*(phi + omega), &sap, &cap);
                __sincosf(0.5f*(phi - omega), &sam, &cam);
                float u00r =  cap*ct, u00i = -sap*ct;
                float u01r = -cam*st, u01i = -sam*st;
                float u10r =  cam*st, u10i = -sam*st;
                float u11r =  cap*ct, u11i =  sap*ct;
                int mask = 1 << (3 - i);
                #pragma unroll
                for (int b = 0; b < 16; ++b) {
                    if (b & mask) continue;
                    int b1 = b | mask;
                    float a0r = re[b],  a0i = im[b];
                    float a1r = re[b1], a1i = im[b1];
                    re[b]  = u00r*a0r - u00i*a0i + u01r*a1r - u01i*a1i;
                    im[b]  = u00r*a0i + u00i*a0r + u01r*a1i + u01i*a1r;
                    re[b1] = u10r*a0r - u10i*a0i + u11r*a1r - u11i*a1i;
                    im[b1] = u10r*a0i + u10i*a0r + u11r*a1i + u11i*a1r;
                }
            }
            #pragma unroll
            for (int b = 0; b < 16; ++b) {
                float sgn = 1.f;
                if ((b & 0xC) == 0xC) sgn = -sgn;
                if ((b & 0x6) == 0x6) sgn = -sgn;
                if ((b & 0x3) == 0x3) sgn = -sgn;
                re[b] *= sgn; im[b] *= sgn;
            }
        }
        #pragma unroll
        for (int b = 0; b < 16; ++b) { W[O_MRE + j*16 + b] = re[b]; W[O_MIM + j*16 + b] = im[b]; }
    }
    __syncthreads();
    {
        int j = tid >> 4, k = tid & 15;
        float sacc = 0.f;
        #pragma unroll
        for (int b = 0; b < 16; ++b) {
            float sg = (b & 8) ? -1.f : 1.f;
            sacc += sg * (W[O_MRE + j*16 + b]*W[O_MRE + k*16 + b] +
                          W[O_MIM + j*16 + b]*W[O_MIM + k*16 + b]);
        }
        W[O_AS + tid] = sacc;
    }
    __syncthreads();

    // ---- mainline: samples sA..sD = base + {0,256,512,768}
    int base = blockIdx.x * 1024 + tid;
    const int sA = (base       < B) ? base       : B - 1;
    const int sB = (base + 256 < B) ? base + 256 : B - 1;
    const int sC = (base + 512 < B) ? base + 512 : B - 1;
    const int sD = (base + 768 < B) ? base + 768 : B - 1;

    const float4* Wi1 = (const float4*)&W[O_IW1];
    const float4* Wi2 = (const float4*)&W[O_IW2];
    const float4* Wt1 = (const float4*)&W[O_TW1];
    const float4* Wt2 = (const float4*)&W[O_TW2];
    const float4* As4 = (const float4*)&W[O_AS];

    // ---- image MLP [48]->relu[64]->[4], quarters of 16 neurons
    v2f imf0[4], imf1[4];
    #pragma unroll
    for (int o = 0; o < 4; ++o) { imf0[o] = vsplat(0.f); imf1[o] = vsplat(0.f); }
    {
        const float4* img4 = (const float4*)image;
        const size_t rA = (size_t)sA * 12, rB = (size_t)sB * 12;
        const size_t rC = (size_t)sC * 12, rD = (size_t)sD * 12;
        for (int q4 = 0; q4 < 4; ++q4) {              // rolled: code-size control
            v2f a0[16], a1[16];
            #pragma unroll
            for (int j = 0; j < 16; ++j) {
                float bv = W[O_IB1 + q4*16 + j];
                a0[j] = vsplat(bv); a1[j] = vsplat(bv);
            }
            #pragma unroll 4
            for (int k4 = 0; k4 < 12; ++k4) {
                float4 xA = img4[rA + k4];
                float4 xB = img4[rB + k4];
                float4 xC = img4[rC + k4];
                float4 xD = img4[rD + k4];
                #pragma unroll
                for (int kk = 0; kk < 4; ++kk) {
                    v2f e0; e0.x = fget(xA, kk); e0.y = fget(xB, kk);
                    v2f e1; e1.x = fget(xC, kk); e1.y = fget(xD, kk);
                    #pragma unroll
                    for (int m = 0; m < 4; ++m) {
                        float4 w = Wi1[(k4*4 + kk)*16 + q4*4 + m];
                        a0[4*m+0] = vfma(e0, w.x, a0[4*m+0]); a1[4*m+0] = vfma(e1, w.x, a1[4*m+0]);
                        a0[4*m+1] = vfma(e0, w.y, a0[4*m+1]); a1[4*m+1] = vfma(e1, w.y, a1[4*m+1]);
                        a0[4*m+2] = vfma(e0, w.z, a0[4*m+2]); a1[4*m+2] = vfma(e1, w.z, a1[4*m+2]);
                        a0[4*m+3] = vfma(e0, w.w, a0[4*m+3]); a1[4*m+3] = vfma(e1, w.w, a1[4*m+3]);
                    }
                }
            }
            #pragma unroll
            for (int j = 0; j < 16; ++j) {
                float4 w2 = Wi2[q4*16 + j];
                v2f r0 = vrelu(a0[j]), r1 = vrelu(a1[j]);
                imf0[0] = vfma(r0, w2.x, imf0[0]); imf1[0] = vfma(r1, w2.x, imf1[0]);
                imf0[1] = vfma(r0, w2.y, imf0[1]); imf1[1] = vfma(r1, w2.y, imf1[1]);
                imf0[2] = vfma(r0, w2.z, imf0[2]); imf1[2] = vfma(r1, w2.z, imf1[2]);
                imf0[3] = vfma(r0, w2.w, imf0[3]); imf1[3] = vfma(r1, w2.w, imf1[3]);
            }
        }
    }

    // ---- text MLP [16]->relu[32]->[4], halves of 16 neurons
    v2f tf0[4], tf1[4];
    #pragma unroll
    for (int o = 0; o < 4; ++o) { tf0[o] = vsplat(0.f); tf1[o] = vsplat(0.f); }
    {
        const float4* txt4 = (const float4*)text;
        const size_t rA = (size_t)sA * 4, rB = (size_t)sB * 4;
        const size_t rC = (size_t)sC * 4, rD = (size_t)sD * 4;
        for (int h2 = 0; h2 < 2; ++h2) {
            v2f a0[16], a1[16];
            #pragma unroll
            for (int j = 0; j < 16; ++j) {
                float bv = W[O_TB1 + h2*16 + j];
                a0[j] = vsplat(bv); a1[j] = vsplat(bv);
            }
            #pragma unroll
            for (int k4 = 0; k4 < 4; ++k4) {
                float4 xA = txt4[rA + k4];
                float4 xB = txt4[rB + k4];
                float4 xC = txt4[rC + k4];
                float4 xD = txt4[rD + k4];
                #pragma unroll
                for (int kk = 0; kk < 4; ++kk) {
                    v2f e0; e0.x = fget(xA, kk); e0.y = fget(xB, kk);
                    v2f e1; e1.x = fget(xC, kk); e1.y = fget(xD, kk);
                    #pragma unroll
                    for (int m = 0; m < 4; ++m) {
                        float4 w = Wt1[(k4*4 + kk)*8 + h2*4 + m];
                        a0[4*m+0] = vfma(e0, w.x, a0[4*m+0]); a1[4*m+0] = vfma(e1, w.x, a1[4*m+0]);
                        a0[4*m+1] = vfma(e0, w.y, a0[4*m+1]); a1[4*m+1] = vfma(e1, w.y, a1[4*m+1]);
                        a0[4*m+2] = vfma(e0, w.z, a0[4*m+2]); a1[4*m+2] = vfma(e1, w.z, a1[4*m+2]);
                        a0[4*m+3] = vfma(e0, w.w, a0[4*m+3]); a1[4*m+3] = vfma(e1, w.w, a1[4*m+3]);
                    }
                }
            }
            #pragma unroll
            for (int j = 0; j < 16; ++j) {
                float4 w2 = Wt2[h2*16 + j];
                v2f r0 = vrelu(a0[j]), r1 = vrelu(a1[j]);
                tf0[0] = vfma(r0, w2.x, tf0[0]); tf1[0] = vfma(r1, w2.x, tf1[0]);
                tf0[1] = vfma(r0, w2.y, tf0[1]); tf1[1] = vfma(r1, w2.y, tf1[1]);
                tf0[2] = vfma(r0, w2.z, tf0[2]); tf1[2] = vfma(r1, w2.z, tf1[2]);
                tf0[3] = vfma(r0, w2.w, tf0[3]); tf1[3] = vfma(r1, w2.w, tf1[3]);
            }
        }
    }

    // ---- quantum expval + head, per packed pair
    float2* o2 = (float2*)out;
    #pragma unroll
    for (int pr = 0; pr < 2; ++pr) {
        v2f c[4], s[4];
        #pragma unroll
        for (int i = 0; i < 4; ++i) {
            v2f f = ((pr ? imf1[i] : imf0[i]) + (pr ? tf1[i] : tf0[i]) + vsplat(W[O_FB2 + i])) * 0.25f;
            float sx, cx, sy, cy;
            __sincosf(f.x, &sx, &cx);
            __sincosf(f.y, &sy, &cy);
            c[i].x = cx; c[i].y = cy; s[i].x = sx; s[i].y = sy;
        }
        v2f p01[4] = { c[0]*c[1], c[0]*s[1], s[0]*c[1], s[0]*s[1] };
        v2f p23[4] = { c[2]*c[3], c[2]*s[3], s[2]*c[3], s[2]*s[3] };
        v2f psi[16];
        #pragma unroll
        for (int x = 0; x < 4; ++x)
            #pragma unroll
            for (int y = 0; y < 4; ++y)
                psi[x*4+y] = p01[x] * p23[y];

        v2f q = vsplat(0.f);
        #pragma unroll
        for (int j = 0; j < 16; ++j) {
            v2f row = vsplat(0.f);
            #pragma unroll
            for (int k4 = 0; k4 < 4; ++k4) {
                float4 a = As4[j*4 + k4];
                row = vfma(psi[k4*4+0], a.x, row);
                row = vfma(psi[k4*4+1], a.y, row);
                row = vfma(psi[k4*4+2], a.z, row);
                row = vfma(psi[k4*4+3], a.w, row);
            }
            q = vfmav(psi[j], row, q);
        }

        v2f o0 = vsplat(W[O_CB2 + 0]), o1v = vsplat(W[O_CB2 + 1]);
        #pragma unroll
        for (int j = 0; j < 16; ++j) {
            float w1 = W[O_CW1 + j], b1 = W[O_CB1 + j];
            v2f h = vrelu(vfma(q, w1, vsplat(b1)));
            o0  = vfma(h, W[O_CW2 + j*2 + 0], o0);
            o1v = vfma(h, W[O_CW2 + j*2 + 1], o1v);
        }
        int sX = base + pr*512, sY = sX + 256;
        if (sX < B) o2[sX] = make_float2(o0.x, o1v.x);
        if (sY < B) o2[sY] = make_float2(o0.y, o1v.y);
    }
}

extern "C" void kernel_launch(void* const* d_in, const int* in_sizes, int n_in,
                              void* d_out, int out_size, void* d_ws, size_t ws_size,
                              hipStream_t stream)
{
    const float* text  = (const float*)d_in[0];
    const float* image = (const float*)d_in[1];
    const float* tW1   = (const float*)d_in[2];
    const float* tb1   = (const float*)d_in[3];
    const float* tW2   = (const float*)d_in[4];
    const float* tb2   = (const float*)d_in[5];
    const float* iW1   = (const float*)d_in[6];
    const float* ib1   = (const float*)d_in[7];
    const float* iW2   = (const float*)d_in[8];
    const float* ib2   = (const float*)d_in[9];
    const float* qw    = (const float*)d_in[10];
    const float* cW1   = (const float*)d_in[11];
    const float* cb1   = (const float*)d_in[12];
    const float* cW2   = (const float*)d_in[13];
    const float* cb2   = (const float*)d_in[14];

    int B = in_sizes[0] / 16;
    int grid = (B + 1023) / 1024;   // 4 samples/thread, 256 threads/block

    qnn_fused<<<grid, 256, 0, stream>>>(
        text, image, tW1, tb1, tW2, tb2, iW1, ib1, iW2, ib2,
        qw, cW1, cb1, cW2, cb2, (float*)d_out, B);
}

// Round 5
// 342.364 us; speedup vs baseline: 2.9778x; 1.2158x over previous
//
#include <hip/hip_runtime.h>
#include <math.h>

#define NQ 4
#define NL 2

// LDS layout (float indices; region starts multiple of 4 -> 16B aligned)
#define O_IW1 0       // 48x64
#define O_IW2 3072    // 64x4
#define O_TW1 3328    // 16x32
#define O_TW2 3840    // 32x4
#define O_IB1 3968    // 64
#define O_TB1 4032    // 32
#define O_FB2 4064    // 4   (ib2+tb2)
#define O_CW1 4068    // 16
#define O_CB1 4084    // 16
#define O_CW2 4100    // 32
#define O_CB2 4132    // 2
#define O_AS  4136    // 16x16
#define O_MRE 4392    // 16x16 scratch
#define O_MIM 4648    // 16x16 scratch
#define LDS_FLOATS 4904

// R5: 1 sample/thread (single pass over inputs, ideal HBM traffic), weights
// broadcast from LDS (wave-uniform ds_read_b128, conflict-free), 128-VGPR
// budget via __launch_bounds__(256,4) -> 4 waves/SIMD, 2048 blocks.
__global__ __launch_bounds__(256, 4) void qnn_fused(
    const float* __restrict__ text, const float* __restrict__ image,
    const float* __restrict__ tW1, const float* __restrict__ tb1,
    const float* __restrict__ tW2, const float* __restrict__ tb2,
    const float* __restrict__ iW1, const float* __restrict__ ib1,
    const float* __restrict__ iW2, const float* __restrict__ ib2,
    const float* __restrict__ qw,
    const float* __restrict__ cW1, const float* __restrict__ cb1,
    const float* __restrict__ cW2, const float* __restrict__ cb2,
    float* __restrict__ out, int B)
{
    __shared__ __align__(16) float W[LDS_FLOATS];
    const int tid = threadIdx.x;

    // ---- stage weights into LDS (coalesced, once per block)
    for (int i = tid; i < 3072; i += 256) W[O_IW1 + i] = iW1[i];
    W[O_IW2 + tid] = iW2[tid];                      // exactly 256
    for (int i = tid; i < 512; i += 256) W[O_TW1 + i] = tW1[i];
    if (tid < 128) W[O_TW2 + tid] = tW2[tid];
    if (tid < 64)  W[O_IB1 + tid] = ib1[tid];
    if (tid < 32)  W[O_TB1 + tid] = tb1[tid];
    if (tid < 4)   W[O_FB2 + tid] = ib2[tid] + tb2[tid];
    if (tid < 16) { W[O_CW1 + tid] = cW1[tid]; W[O_CB1 + tid] = cb1[tid]; }
    if (tid < 32)  W[O_CW2 + tid] = cW2[tid];
    if (tid < 2)   W[O_CB2 + tid] = cb2[tid];

    // ---- simulate circuit columns (threads 0-15), in parallel with staging
    if (tid < 16) {
        const int j = tid;
        float re[16], im[16];
        #pragma unroll
        for (int b = 0; b < 16; ++b) { re[b] = (b == j) ? 1.f : 0.f; im[b] = 0.f; }
        for (int l = 0; l < NL; ++l) {
            for (int i = 0; i < NQ; ++i) {
                float phi   = qw[(l*NQ + i)*3 + 0];
                float theta = qw[(l*NQ + i)*3 + 1];
                float omega = qw[(l*NQ + i)*3 + 2];
                float ct, st; __sincosf(0.5f*theta, &st, &ct);
                float cap, sap, cam, sam;
                __sincosf(0.5f*(phi + omega), &sap, &cap);
                __sincosf(0.5f*(phi - omega), &sam, &cam);
                float u00r =  cap*ct, u00i = -sap*ct;
                float u01r = -cam*st, u01i = -sam*st;
                float u10r =  cam*st, u10i = -sam*st;
                float u11r =  cap*ct, u11i =  sap*ct;
                int mask = 1 << (3 - i);
                #pragma unroll
                for (int b = 0; b < 16; ++b) {
                    if (b & mask) continue;
                    int b1 = b | mask;
                    float a0r = re[b],  a0i = im[b];
                    float a1r = re[b1], a1i = im[b1];
                    re[b]  = u00r*a0r - u00i*a0i + u01r*a1r - u01i*a1i;
                    im[b]  = u00r*a0i + u00i*a0r + u01r*a1i + u01i*a1r;
                    re[b1] = u10r*a0r - u10i*a0i + u11r*a1r - u11i*a1i;
                    im[b1] = u10r*a0i + u10i*a0r + u11r*a1i + u11i*a1r;
                }
            }
            #pragma unroll
            for (int b = 0; b < 16; ++b) {   // CZ chain masks 0xC,0x6,0x3
                float sgn = 1.f;
                if ((b & 0xC) == 0xC) sgn = -sgn;
                if ((b & 0x6) == 0x6) sgn = -sgn;
                if ((b & 0x3) == 0x3) sgn = -sgn;
                re[b] *= sgn; im[b] *= sgn;
            }
        }
        #pragma unroll
        for (int b = 0; b < 16; ++b) { W[O_MRE + j*16 + b] = re[b]; W[O_MIM + j*16 + b] = im[b]; }
    }
    __syncthreads();
    {   // A[j][k] = sum_b sign(b3) * Re(conj(M[b][j]) M[b][k]), 1 entry/thread
        int j = tid >> 4, k = tid & 15;
        float sacc = 0.f;
        #pragma unroll
        for (int b = 0; b < 16; ++b) {
            float sg = (b & 8) ? -1.f : 1.f;
            sacc += sg * (W[O_MRE + j*16 + b]*W[O_MRE + k*16 + b] +
                          W[O_MIM + j*16 + b]*W[O_MIM + k*16 + b]);
        }
        W[O_AS + tid] = sacc;
    }
    __syncthreads();

    // ---- mainline: 1 sample per thread
    const int s = blockIdx.x * 256 + tid;
    const int cs = (s < B) ? s : (B - 1);

    const float4* Wi1 = (const float4*)&W[O_IW1];
    const float4* Wi2 = (const float4*)&W[O_IW2];
    const float4* Wt1 = (const float4*)&W[O_TW1];
    const float4* Wt2 = (const float4*)&W[O_TW2];
    const float4* Bi1 = (const float4*)&W[O_IB1];
    const float4* Bt1 = (const float4*)&W[O_TB1];
    const float4* As4 = (const float4*)&W[O_AS];

    // ---- image MLP: [48] -> relu[64] -> [4], full 64 accumulators
    float acc[64];
    #pragma unroll
    for (int j4 = 0; j4 < 16; ++j4) {
        float4 bv = Bi1[j4];
        acc[4*j4] = bv.x; acc[4*j4+1] = bv.y; acc[4*j4+2] = bv.z; acc[4*j4+3] = bv.w;
    }
    {
        const float4* xg = (const float4*)(image + (size_t)cs * 48);
        #pragma unroll 2
        for (int k4 = 0; k4 < 12; ++k4) {
            float4 x = xg[k4];
            #pragma unroll
            for (int kk = 0; kk < 4; ++kk) {
                float e = (kk == 0) ? x.x : (kk == 1) ? x.y : (kk == 2) ? x.z : x.w;
                const float4* wr = Wi1 + (k4*4 + kk)*16;
                #pragma unroll
                for (int j4 = 0; j4 < 16; ++j4) {
                    float4 w = wr[j4];
                    acc[4*j4+0] = fmaf(e, w.x, acc[4*j4+0]);
                    acc[4*j4+1] = fmaf(e, w.y, acc[4*j4+1]);
                    acc[4*j4+2] = fmaf(e, w.z, acc[4*j4+2]);
                    acc[4*j4+3] = fmaf(e, w.w, acc[4*j4+3]);
                }
            }
        }
    }
    float f0, f1, f2, f3;   // feats accumulators (start from fused ib2+tb2)
    f0 = W[O_FB2+0]; f1 = W[O_FB2+1]; f2 = W[O_FB2+2]; f3 = W[O_FB2+3];
    #pragma unroll
    for (int j = 0; j < 64; ++j) {
        float r = fmaxf(acc[j], 0.f);
        float4 w2 = Wi2[j];
        f0 = fmaf(r, w2.x, f0); f1 = fmaf(r, w2.y, f1);
        f2 = fmaf(r, w2.z, f2); f3 = fmaf(r, w2.w, f3);
    }

    // ---- text MLP: [16] -> relu[32] -> [4], reuse acc[0..31]
    #pragma unroll
    for (int j4 = 0; j4 < 8; ++j4) {
        float4 bv = Bt1[j4];
        acc[4*j4] = bv.x; acc[4*j4+1] = bv.y; acc[4*j4+2] = bv.z; acc[4*j4+3] = bv.w;
    }
    {
        const float4* xg = (const float4*)(text + (size_t)cs * 16);
        #pragma unroll
        for (int k4 = 0; k4 < 4; ++k4) {
            float4 x = xg[k4];
            #pragma unroll
            for (int kk = 0; kk < 4; ++kk) {
                float e = (kk == 0) ? x.x : (kk == 1) ? x.y : (kk == 2) ? x.z : x.w;
                const float4* wr = Wt1 + (k4*4 + kk)*8;
                #pragma unroll
                for (int j4 = 0; j4 < 8; ++j4) {
                    float4 w = wr[j4];
                    acc[4*j4+0] = fmaf(e, w.x, acc[4*j4+0]);
                    acc[4*j4+1] = fmaf(e, w.y, acc[4*j4+1]);
                    acc[4*j4+2] = fmaf(e, w.z, acc[4*j4+2]);
                    acc[4*j4+3] = fmaf(e, w.w, acc[4*j4+3]);
                }
            }
        }
    }
    #pragma unroll
    for (int j = 0; j < 32; ++j) {
        float r = fmaxf(acc[j], 0.f);
        float4 w2 = Wt2[j];
        f0 = fmaf(r, w2.x, f0); f1 = fmaf(r, w2.y, f1);
        f2 = fmaf(r, w2.z, f2); f3 = fmaf(r, w2.w, f3);
    }

    // ---- quantum expval: angle_i = feats_i * 0.5 * 0.5
    float c0,s0v,c1,s1v,c2,s2v,c3,s3v;
    __sincosf(f0 * 0.25f, &s0v, &c0);
    __sincosf(f1 * 0.25f, &s1v, &c1);
    __sincosf(f2 * 0.25f, &s2v, &c2);
    __sincosf(f3 * 0.25f, &s3v, &c3);
    float p01[4] = { c0*c1, c0*s1v, s0v*c1, s0v*s1v };
    float p23[4] = { c2*c3, c2*s3v, s2v*c3, s2v*s3v };
    float psi[16];
    #pragma unroll
    for (int x = 0; x < 4; ++x)
        #pragma unroll
        for (int y = 0; y < 4; ++y)
            psi[x*4+y] = p01[x] * p23[y];

    float q = 0.f;
    #pragma unroll
    for (int j = 0; j < 16; ++j) {
        float row = 0.f;
        #pragma unroll
        for (int k4 = 0; k4 < 4; ++k4) {
            float4 a = As4[j*4 + k4];
            row = fmaf(a.x, psi[k4*4+0], row);
            row = fmaf(a.y, psi[k4*4+1], row);
            row = fmaf(a.z, psi[k4*4+2], row);
            row = fmaf(a.w, psi[k4*4+3], row);
        }
        q = fmaf(psi[j], row, q);
    }

    // ---- classifier head
    float o0 = W[O_CB2+0], o1 = W[O_CB2+1];
    #pragma unroll
    for (int j = 0; j < 16; ++j) {
        float h = fmaxf(fmaf(q, W[O_CW1+j], W[O_CB1+j]), 0.f);
        o0 = fmaf(h, W[O_CW2 + j*2 + 0], o0);
        o1 = fmaf(h, W[O_CW2 + j*2 + 1], o1);
    }
    if (s < B) ((float2*)out)[s] = make_float2(o0, o1);
}

extern "C" void kernel_launch(void* const* d_in, const int* in_sizes, int n_in,
                              void* d_out, int out_size, void* d_ws, size_t ws_size,
                              hipStream_t stream)
{
    const float* text  = (const float*)d_in[0];
    const float* image = (const float*)d_in[1];
    const float* tW1   = (const float*)d_in[2];
    const float* tb1   = (const float*)d_in[3];
    const float* tW2   = (const float*)d_in[4];
    const float* tb2   = (const float*)d_in[5];
    const float* iW1   = (const float*)d_in[6];
    const float* ib1   = (const float*)d_in[7];
    const float* iW2   = (const float*)d_in[8];
    const float* ib2   = (const float*)d_in[9];
    const float* qw    = (const float*)d_in[10];
    const float* cW1   = (const float*)d_in[11];
    const float* cb1   = (const float*)d_in[12];
    const float* cW2   = (const float*)d_in[13];
    const float* cb2   = (const float*)d_in[14];

    int B = in_sizes[0] / 16;
    int grid = (B + 255) / 256;   // 1 sample/thread

    qnn_fused<<<grid, 256, 0, stream>>>(
        text, image, tW1, tb1, tW2, tb2, iW1, ib1, iW2, ib2,
        qw, cW1, cb1, cW2, cb2, (float*)d_out, B);
}

// Round 6
// 268.525 us; speedup vs baseline: 3.7967x; 1.2750x over previous
//
#include <hip/hip_runtime.h>
#include <math.h>

#define NQ 4
#define NL 2

// LDS float-index offsets
#define O_IMG 0        // 256 samples x 48 floats (row stride 48)
#define O_AS  12288    // 16x16 A matrix
#define O_MRE 12544    // 16x16 circuit scratch
#define O_MIM 12800    // 16x16 circuit scratch
#define LDS_FLOATS 13056   // 52224 B -> 3 blocks/CU, 12 waves/CU

// R6: 1 sample/thread. Weights via wave-uniform global reads (compiler
// scalarizes to s_load; SGPR operand feeds v_fma -> zero VGPR cost).
// Image row staged once in LDS, hidden layer strip-mined 2x32 so the
// frame fits 64 arch VGPRs (no scratch, no AGPR shuffling).
__global__ __launch_bounds__(256, 4) void qnn_fused(
    const float* __restrict__ text, const float* __restrict__ image,
    const float* __restrict__ tW1, const float* __restrict__ tb1,
    const float* __restrict__ tW2, const float* __restrict__ tb2,
    const float* __restrict__ iW1, const float* __restrict__ ib1,
    const float* __restrict__ iW2, const float* __restrict__ ib2,
    const float* __restrict__ qw,
    const float* __restrict__ cW1, const float* __restrict__ cb1,
    const float* __restrict__ cW2, const float* __restrict__ cb2,
    float* __restrict__ out, int B)
{
    __shared__ __align__(16) float S[LDS_FLOATS];
    const int tid = threadIdx.x;

    // ---- stage this block's image rows into LDS (fully coalesced)
    {
        const int sbase = blockIdx.x * 256;
        #pragma unroll
        for (int j = 0; j < 12; ++j) {
            int flat = j * 256 + tid;          // 0..3071, consecutive per wave
            int sl = flat / 12;                 // magic-mul, cheap
            int c  = flat - sl * 12;
            int sg = sbase + sl; if (sg >= B) sg = B - 1;
            float4 v = ((const float4*)image)[(size_t)sg * 12 + c];
            *(float4*)&S[O_IMG + sl * 48 + c * 4] = v;   // contiguous -> conflict-free
        }
    }

    // ---- circuit sim: 16 basis columns (threads 0-15; overlaps staging)
    if (tid < 16) {
        const int j = tid;
        float re[16], im[16];
        #pragma unroll
        for (int b = 0; b < 16; ++b) { re[b] = (b == j) ? 1.f : 0.f; im[b] = 0.f; }
        for (int l = 0; l < NL; ++l) {
            for (int i = 0; i < NQ; ++i) {
                float phi   = qw[(l*NQ + i)*3 + 0];
                float theta = qw[(l*NQ + i)*3 + 1];
                float omega = qw[(l*NQ + i)*3 + 2];
                float ct, st; __sincosf(0.5f*theta, &st, &ct);
                float cap, sap, cam, sam;
                __sincosf(0.5f*(phi + omega), &sap, &cap);
                __sincosf(0.5f*(phi - omega), &sam, &cam);
                float u00r =  cap*ct, u00i = -sap*ct;
                float u01r = -cam*st, u01i = -sam*st;
                float u10r =  cam*st, u10i = -sam*st;
                float u11r =  cap*ct, u11i =  sap*ct;
                int mask = 1 << (3 - i);
                #pragma unroll
                for (int b = 0; b < 16; ++b) {
                    if (b & mask) continue;
                    int b1 = b | mask;
                    float a0r = re[b],  a0i = im[b];
                    float a1r = re[b1], a1i = im[b1];
                    re[b]  = u00r*a0r - u00i*a0i + u01r*a1r - u01i*a1i;
                    im[b]  = u00r*a0i + u00i*a0r + u01r*a1i + u01i*a1r;
                    re[b1] = u10r*a0r - u10i*a0i + u11r*a1r - u11i*a1i;
                    im[b1] = u10r*a0i + u10i*a0r + u11r*a1i + u11i*a1r;
                }
            }
            #pragma unroll
            for (int b = 0; b < 16; ++b) {   // CZ chain masks 0xC,0x6,0x3
                float sgn = 1.f;
                if ((b & 0xC) == 0xC) sgn = -sgn;
                if ((b & 0x6) == 0x6) sgn = -sgn;
                if ((b & 0x3) == 0x3) sgn = -sgn;
                re[b] *= sgn; im[b] *= sgn;
            }
        }
        #pragma unroll
        for (int b = 0; b < 16; ++b) { S[O_MRE + j*16 + b] = re[b]; S[O_MIM + j*16 + b] = im[b]; }
    }
    __syncthreads();
    {   // A[j][k] = sum_b sign(b3) Re(conj(M[b][j]) M[b][k]); 1 entry/thread
        int j = tid >> 4, k = tid & 15;
        float sacc = 0.f;
        #pragma unroll
        for (int b = 0; b < 16; ++b) {
            float sg = (b & 8) ? -1.f : 1.f;
            sacc += sg * (S[O_MRE + j*16 + b]*S[O_MRE + k*16 + b] +
                          S[O_MIM + j*16 + b]*S[O_MIM + k*16 + b]);
        }
        S[O_AS + tid] = sacc;
    }
    __syncthreads();

    // ---- mainline: 1 sample/thread
    const int s  = blockIdx.x * 256 + tid;
    const int cs = (s < B) ? s : (B - 1);

    // text row -> registers (16 floats)
    float xt[16];
    {
        const float4* tg = (const float4*)(text + (size_t)cs * 16);
        #pragma unroll
        for (int k4 = 0; k4 < 4; ++k4) {
            float4 v = tg[k4];
            xt[4*k4] = v.x; xt[4*k4+1] = v.y; xt[4*k4+2] = v.z; xt[4*k4+3] = v.w;
        }
    }

    // feats accumulators, init with fused second-layer biases (uniform s_load)
    float f0 = ib2[0] + tb2[0];
    float f1 = ib2[1] + tb2[1];
    float f2 = ib2[2] + tb2[2];
    float f3 = ib2[3] + tb2[3];

    // ---- image MLP [48]->relu[64]->[4], two groups of 32 neurons
    for (int g = 0; g < 2; ++g) {
        float acc[32];
        #pragma unroll
        for (int j = 0; j < 32; ++j) acc[j] = ib1[g*32 + j];
        #pragma unroll 2
        for (int k4 = 0; k4 < 12; ++k4) {
            float4 xv = *(const float4*)&S[O_IMG + tid*48 + k4*4];
            #pragma unroll
            for (int kk = 0; kk < 4; ++kk) {
                float e = (kk == 0) ? xv.x : (kk == 1) ? xv.y : (kk == 2) ? xv.z : xv.w;
                const float* wr = iW1 + (k4*4 + kk)*64 + g*32;   // uniform -> s_load
                #pragma unroll
                for (int j = 0; j < 32; ++j)
                    acc[j] = fmaf(e, wr[j], acc[j]);
            }
        }
        #pragma unroll
        for (int j = 0; j < 32; ++j) {
            float r = fmaxf(acc[j], 0.f);
            const float* w2 = iW2 + (g*32 + j)*4;                // uniform -> s_load
            f0 = fmaf(r, w2[0], f0); f1 = fmaf(r, w2[1], f1);
            f2 = fmaf(r, w2[2], f2); f3 = fmaf(r, w2[3], f3);
        }
    }

    // ---- text MLP [16]->relu[32]->[4], two groups of 16 neurons
    for (int g = 0; g < 2; ++g) {
        float acc[16];
        #pragma unroll
        for (int j = 0; j < 16; ++j) acc[j] = tb1[g*16 + j];
        #pragma unroll 4
        for (int k = 0; k < 16; ++k) {
            const float* wr = tW1 + k*32 + g*16;                 // uniform -> s_load
            float e = xt[k];
            #pragma unroll
            for (int j = 0; j < 16; ++j)
                acc[j] = fmaf(e, wr[j], acc[j]);
        }
        #pragma unroll
        for (int j = 0; j < 16; ++j) {
            float r = fmaxf(acc[j], 0.f);
            const float* w2 = tW2 + (g*16 + j)*4;                // uniform -> s_load
            f0 = fmaf(r, w2[0], f0); f1 = fmaf(r, w2[1], f1);
            f2 = fmaf(r, w2[2], f2); f3 = fmaf(r, w2[3], f3);
        }
    }

    // ---- quantum expval: angle_i = feats_i * 0.25 (feats*0.5, angle*0.5)
    float c0,s0v,c1,s1v,c2,s2v,c3,s3v;
    __sincosf(f0 * 0.25f, &s0v, &c0);
    __sincosf(f1 * 0.25f, &s1v, &c1);
    __sincosf(f2 * 0.25f, &s2v, &c2);
    __sincosf(f3 * 0.25f, &s3v, &c3);
    float p01[4] = { c0*c1, c0*s1v, s0v*c1, s0v*s1v };
    float p23[4] = { c2*c3, c2*s3v, s2v*c3, s2v*s3v };
    float psi[16];
    #pragma unroll
    for (int x = 0; x < 4; ++x)
        #pragma unroll
        for (int y = 0; y < 4; ++y)
            psi[x*4+y] = p01[x] * p23[y];

    float q = 0.f;
    #pragma unroll
    for (int j = 0; j < 16; ++j) {
        float row = 0.f;
        #pragma unroll
        for (int k4 = 0; k4 < 4; ++k4) {
            float4 a = *(const float4*)&S[O_AS + j*16 + k4*4];   // LDS broadcast
            row = fmaf(a.x, psi[k4*4+0], row);
            row = fmaf(a.y, psi[k4*4+1], row);
            row = fmaf(a.z, psi[k4*4+2], row);
            row = fmaf(a.w, psi[k4*4+3], row);
        }
        q = fmaf(psi[j], row, q);
    }

    // ---- classifier head (weights uniform -> s_load)
    float o0 = cb2[0], o1 = cb2[1];
    #pragma unroll
    for (int j = 0; j < 16; ++j) {
        float h = fmaxf(fmaf(q, cW1[j], cb1[j]), 0.f);
        o0 = fmaf(h, cW2[j*2 + 0], o0);
        o1 = fmaf(h, cW2[j*2 + 1], o1);
    }
    if (s < B) ((float2*)out)[s] = make_float2(o0, o1);
}

extern "C" void kernel_launch(void* const* d_in, const int* in_sizes, int n_in,
                              void* d_out, int out_size, void* d_ws, size_t ws_size,
                              hipStream_t stream)
{
    const float* text  = (const float*)d_in[0];
    const float* image = (const float*)d_in[1];
    const float* tW1   = (const float*)d_in[2];
    const float* tb1   = (const float*)d_in[3];
    const float* tW2   = (const float*)d_in[4];
    const float* tb2   = (const float*)d_in[5];
    const float* iW1   = (const float*)d_in[6];
    const float* ib1   = (const float*)d_in[7];
    const float* iW2   = (const float*)d_in[8];
    const float* ib2   = (const float*)d_in[9];
    const float* qw    = (const float*)d_in[10];
    const float* cW1   = (const float*)d_in[11];
    const float* cb1   = (const float*)d_in[12];
    const float* cW2   = (const float*)d_in[13];
    const float* cb2   = (const float*)d_in[14];

    int B = in_sizes[0] / 16;
    int grid = (B + 255) / 256;   // 1 sample/thread

    qnn_fused<<<grid, 256, 0, stream>>>(
        text, image, tW1, tb1, tW2, tb2, iW1, ib1, iW2, ib2,
        qw, cW1, cb1, cW2, cb2, (float*)d_out, B);
}